// Round 8
// baseline (425.923 us; speedup 1.0000x reference)
//
#include <hip/hip_runtime.h>

// Fusin_Dice_rank — single fused kernel.
// Keys: order-preserving u32 ord(d), d = x1-x0 (monotone with p=sigmoid(d)).
// t binary -> element feeds exactly ONE top-k problem:
//   A (t==0): key o=ordf(d);  B (t==1): key ~o = ordf(-d).
// Per block (1/64th of a sample): stream inputs, dice partials, static
// threshold filter (d>=3.5) with per-block LDS compaction -> TRANSPOSED
// global candidate store [CAP_B][2048] (coalesced finisher reads).
// Last-finishing block per sample (padded done counter) inline-finishes:
// wave0 dice, wave1/2 wave-local exact binary-search top-30, hinge, sample
// store. Last sample's finisher reduces 32 samples -> out.
// Exact whole-sample fallback if the filter under/overflows (unreachable on
// bench data, required for arbitrary inputs).

#define N_ELEM (512 * 512)
#define B_SAMPLES 32
#define CHUNK 4096
#define BLOCKS_PER_S 64
#define NBLK (B_SAMPLES * BLOCKS_PER_S)   // 2048
#define TOPK 30
#define CAP_B 64                          // per-block candidate cap (mean ~13.7)
#define LCAP2 2048                        // per-sample gather cap (mean ~874, >30 sigma)
// ordf(3.5f): 3.5f = 0x40600000, positive -> | 0x80000000
#define THR_KEY 0xC0600000u

// ws layout in u32 units
#define PART_OFF 0                                // [2048][3] f32
#define CNTA_OFF (PART_OFF + NBLK * 3)            // [2048] u32
#define CNTB_OFF (CNTA_OFF + NBLK)                // [2048] u32
#define CANDA_OFF (CNTB_OFF + NBLK)               // [CAP_B][2048] u32 (transposed)
#define CANDB_OFF (CANDA_OFF + CAP_B * NBLK)
#define SAMP_OFF (CANDB_OFF + CAP_B * NBLK)       // [32][2] f32
#define SCTR_OFF (SAMP_OFF + B_SAMPLES * 2)       // [32] done ctrs, stride 16 u32 (64B)
#define DONEG_OFF (SCTR_OFF + B_SAMPLES * 16)     // [1] u32

__device__ __forceinline__ unsigned ordf(float f) {
    unsigned u = __float_as_uint(f);
    return (u & 0x80000000u) ? ~u : (u | 0x80000000u);
}

__device__ __forceinline__ float invord_sigmoid(unsigned u) {
    if (u == 0u) return 0.0f;
    unsigned b = (u & 0x80000000u) ? (u ^ 0x80000000u) : ~u;
    float f = __uint_as_float(b);
    return 1.0f / (1.0f + __expf(-f));
}

__device__ __forceinline__ unsigned long long shflxor_u64(unsigned long long v, int off) {
    unsigned lo = (unsigned)v, hi = (unsigned)(v >> 32);
    lo = __shfl_xor(lo, off, 64);
    hi = __shfl_xor(hi, off, 64);
    return ((unsigned long long)hi << 32) | lo;
}

// Exact top-30: 30 rounds of block argmax over the whole sample (fallback).
__device__ void fallback30(const float* __restrict__ x0p, const float* __restrict__ x1p,
                           const float* __restrict__ tp, int isB, float* dst,
                           int tid, int lane, int wid, unsigned long long* sred) {
    unsigned long long prev = ~0ull;
    for (int r = 0; r < TOPK; ++r) {
        unsigned long long best = 0ull;
        for (int e = tid; e < N_ELEM; e += 256) {
            float d = x1p[e] - x0p[e];
            float t = tp[e];
            unsigned key;
            if (isB) key = (t != 0.0f) ? ordf(-d) : 0u;
            else     key = (t == 0.0f) ? ordf(d) : 0u;
            unsigned long long pk = ((unsigned long long)key << 18) | (unsigned)e;
            if (pk < prev && pk > best) best = pk;
        }
        for (int off = 32; off; off >>= 1) {
            unsigned long long v = shflxor_u64(best, off);
            if (v > best) best = v;
        }
        if (lane == 0) sred[wid] = best;
        __syncthreads();
        unsigned long long b0 = sred[0];
#pragma unroll
        for (int w = 1; w < 4; ++w) if (sred[w] > b0) b0 = sred[w];
        __syncthreads();
        if (tid == 0) dst[r] = invord_sigmoid((unsigned)(b0 >> 18));
        prev = b0;
    }
}

// Wave-local exact top-30 over one sample's TRANSPOSED candidate lists.
// candG = &ws[CAND?_OFF + s*64]: item i of block (s*64+lane) at candG[i*NBLK+lane]
// (coalesced across lanes). No barriers. flag: >=0 ok, -1 -> fallback needed.
__device__ void wave_select_t(const unsigned* __restrict__ candG,
                              const unsigned* __restrict__ cntG,   // [64]
                              unsigned* lbuf,                      // LDS [LCAP2]
                              unsigned* rbuf,                      // LDS [TOPK]
                              int* rcnt,                           // LDS, pre-zeroed
                              int* flag,                           // LDS
                              float* dst,                          // [TOPK]
                              int lane) {
    int cvr = (int)cntG[lane];
    int cv = min(cvr, CAP_B);
    unsigned long long ovb = __ballot(cvr > CAP_B);
    int pe = cv;
#pragma unroll
    for (int off = 1; off < 64; off <<= 1) {
        int v = __shfl_up(pe, off, 64);
        if (lane >= off) pe += v;
    }
    const int n = __shfl(pe, 63, 64);
    const int pf = pe - cv;
    if (n < TOPK || n > LCAP2 || ovb != 0ull) {
        if (lane == 0) *flag = -1;
        return;
    }
    if (lane == 0) *flag = n;
    // coalesced gather into LDS
    for (int i = 0; i < cv; ++i) lbuf[pf + i] = candG[i * NBLK + lane];
    // wave max to tighten the search range
    unsigned mx = 0u;
    for (int i = lane; i < n; i += 64) mx = max(mx, lbuf[i]);
#pragma unroll
    for (int off = 32; off; off >>= 1) mx = max(mx, (unsigned)__shfl_xor((int)mx, off, 64));
    // binary search: largest lo with count(key >= lo) >= TOPK
    unsigned lo = THR_KEY, hi = mx + 1u;
    while (hi - lo > 1u) {
        unsigned mid = lo + ((hi - lo) >> 1);
        int cnum = 0;
        for (int i = lane; i < n; i += 64) cnum += (lbuf[i] >= mid);
#pragma unroll
        for (int off = 32; off; off >>= 1) cnum += __shfl_xor(cnum, off, 64);
        if (cnum >= TOPK) lo = mid; else hi = mid;
    }
    int ch = 0;
    for (int i = lane; i < n; i += 64) ch += (lbuf[i] > lo);
#pragma unroll
    for (int off = 32; off; off >>= 1) ch += __shfl_xor(ch, off, 64);
    for (int i = lane; i < n; i += 64) {
        unsigned k = lbuf[i];
        if (k > lo) { int pos = atomicAdd(rcnt, 1); rbuf[pos] = k; }
    }
    if (lane < TOPK - ch) rbuf[ch + lane] = lo;
    // deterministic rank-sort -> dst descending
    if (lane < TOPK) {
        unsigned key = rbuf[lane];
        int rank = 0;
#pragma unroll
        for (int j = 0; j < TOPK; ++j) {
            unsigned kj = rbuf[j];
            rank += (kj > key) || (kj == key && j < lane);
        }
        dst[rank] = invord_sigmoid(key);
    }
}

__global__ __launch_bounds__(256) void fused(const float* __restrict__ pred,
                                             const float* __restrict__ tgt,
                                             float* __restrict__ wsf,
                                             float* __restrict__ out) {
    unsigned* wsu = (unsigned*)wsf;
    const int s = blockIdx.x >> 6, c = blockIdx.x & 63;
    const int tid = threadIdx.x, lane = tid & 63, wid = tid >> 6;

    __shared__ float red[12];
    __shared__ int shCntA, shCntB;
    __shared__ unsigned LA_s[CAP_B], LB_s[CAP_B];
    __shared__ unsigned LA2[LCAP2], LB2[LCAP2];   // 16 KB (finisher only)
    __shared__ unsigned RA[TOPK], RB[TOPK];
    __shared__ int rcA, rcB, flagA, flagB, shLast, shDoneAll;
    __shared__ float ntop[TOPK], pv[TOPK], fred[8];
    __shared__ unsigned long long sred[4];

    if (tid == 0) { shCntA = 0; shCntB = 0; }

    // ---------------- streaming phase ----------------
    const float* x0p = pred + (size_t)s * 2 * N_ELEM + (size_t)c * CHUNK;
    const float* x1p = x0p + N_ELEM;
    const float* tp  = tgt + (size_t)s * N_ELEM + (size_t)c * CHUNK;

    unsigned o[16];
    unsigned tmask = 0u;
    float sp = 0.f, spt = 0.f;

#pragma unroll
    for (int j = 0; j < 4; ++j) {
        float4 X0 = ((const float4*)x0p)[j * 256 + tid];
        float4 X1 = ((const float4*)x1p)[j * 256 + tid];
        float4 T  = ((const float4*)tp )[j * 256 + tid];
#define PROC(q, xx0, xx1, tt)                                  \
        {                                                      \
            float d = (xx1) - (xx0);                           \
            float p = 1.0f / (1.0f + __expf(-d));              \
            sp += p; spt = fmaf(p, (tt), spt);                 \
            o[j * 4 + (q)] = ordf(d);                          \
            if ((tt) != 0.0f) tmask |= 1u << (j * 4 + (q));    \
        }
        PROC(0, X0.x, X1.x, T.x)
        PROC(1, X0.y, X1.y, T.y)
        PROC(2, X0.z, X1.z, T.z)
        PROC(3, X0.w, X1.w, T.w)
#undef PROC
    }
    float st = (float)__popc(tmask);

    for (int off = 32; off; off >>= 1) {
        sp  += __shfl_xor(sp, off, 64);
        st  += __shfl_xor(st, off, 64);
        spt += __shfl_xor(spt, off, 64);
    }
    if (lane == 0) { red[wid * 3] = sp; red[wid * 3 + 1] = st; red[wid * 3 + 2] = spt; }
    __syncthreads();  // counters zeroed + red visible

    // threshold emit to per-block LDS buffers (~27 passers/block)
#pragma unroll
    for (int e = 0; e < 16; ++e) {
        unsigned key = o[e];
        if ((tmask >> e) & 1u) {
            unsigned kb = ~key;                    // == ordf(-d)
            if (kb >= THR_KEY) {
                int pos = atomicAdd(&shCntB, 1);
                if (pos < CAP_B) LB_s[pos] = kb;
            }
        } else {
            if (key >= THR_KEY) {
                int pos = atomicAdd(&shCntA, 1);
                if (pos < CAP_B) LA_s[pos] = key;
            }
        }
    }
    __syncthreads();

    const int blk = s * BLOCKS_PER_S + c;
    const int nA = shCntA, nB = shCntB;
    if (tid == 0) {
        float a = 0.f, b = 0.f, cc = 0.f;
#pragma unroll
        for (int w = 0; w < 4; ++w) { a += red[w * 3]; b += red[w * 3 + 1]; cc += red[w * 3 + 2]; }
        float* part = wsf + PART_OFF + (size_t)blk * 3;
        part[0] = a; part[1] = b; part[2] = cc;
        wsu[CNTA_OFF + blk] = (unsigned)nA;   // raw count: >CAP_B flags fallback
        wsu[CNTB_OFF + blk] = (unsigned)nB;
    }
    // transposed candidate store: item i of block blk at [i*NBLK + blk]
    if (tid < CAP_B) {
        if (tid < min(nA, CAP_B)) wsu[CANDA_OFF + (size_t)tid * NBLK + blk] = LA_s[tid];
        if (tid < min(nB, CAP_B)) wsu[CANDB_OFF + (size_t)tid * NBLK + blk] = LB_s[tid];
    }

    // ---------------- last-block-per-sample finisher ----------------
    __threadfence();
    if (tid == 0)
        shLast = (atomicAdd(&wsu[SCTR_OFF + s * 16], 1u) == BLOCKS_PER_S - 1u);
    __syncthreads();
    if (!shLast) return;
    __threadfence();  // acquire: other blocks' candidates/partials

    if (tid == 0) { rcA = 0; rcB = 0; flagA = 0; flagB = 0; }
    __syncthreads();

    if (wid == 0) {
        const float* part = wsf + PART_OFF + (size_t)(s * BLOCKS_PER_S + lane) * 3;
        float a = part[0], b = part[1], cc = part[2];
        for (int off = 32; off; off >>= 1) {
            a  += __shfl_xor(a, off, 64);
            b  += __shfl_xor(b, off, 64);
            cc += __shfl_xor(cc, off, 64);
        }
        if (lane == 0) { fred[0] = a; fred[1] = b; fred[2] = cc; }
    } else if (wid == 1) {
        wave_select_t(wsu + CANDA_OFF + s * BLOCKS_PER_S,
                      wsu + CNTA_OFF + s * BLOCKS_PER_S,
                      LA2, RA, &rcA, &flagA, ntop, lane);
    } else if (wid == 2) {
        wave_select_t(wsu + CANDB_OFF + s * BLOCKS_PER_S,
                      wsu + CNTB_OFF + s * BLOCKS_PER_S,
                      LB2, RB, &rcB, &flagB, pv, lane);
    }
    __syncthreads();

    // block-uniform fallbacks (unreachable on bench data)
    if (flagA < 0) {
        const float* b0 = pred + (size_t)s * 2 * N_ELEM;
        fallback30(b0, b0 + N_ELEM, tgt + (size_t)s * N_ELEM, 0, ntop, tid, lane, wid, sred);
    }
    if (flagB < 0) {
        const float* b0 = pred + (size_t)s * 2 * N_ELEM;
        fallback30(b0, b0 + N_ELEM, tgt + (size_t)s * N_ELEM, 1, pv, tid, lane, wid, sred);
    }
    __syncthreads();

    // 30x30 hinge sum
    float rs = 0.f;
    for (int pch = tid; pch < TOPK * TOPK; pch += 256) {
        int i = pch / TOPK, j = pch - i * TOPK;
        float th = ntop[i] - (1.0f - pv[j]) + 0.3f;
        rs += fmaxf(th, 0.0f);
    }
    for (int off = 32; off; off >>= 1) rs += __shfl_xor(rs, off, 64);
    if (lane == 0) fred[4 + wid] = rs;
    __syncthreads();

    if (tid == 0) {
        float SP = fred[0], ST = fred[1], SPT = fred[2];
        float RS = fred[4] + fred[5] + fred[6] + fred[7];
        const float Nf = (float)N_ELEM;
        float dice1 = 1.0f - 2.0f * SPT / (SP + ST + 1e-5f);
        float dice0 = 1.0f - 2.0f * (Nf - SP - ST + SPT) / ((Nf - SP) + (Nf - ST) + 1e-5f);
        float* samp = wsf + SAMP_OFF + s * 2;
        samp[0] = dice0 + dice1;
        samp[1] = RS;
    }

    // ---------------- last-sample global finalize ----------------
    __threadfence();
    if (tid == 0) shDoneAll = (atomicAdd(&wsu[DONEG_OFF], 1u) == B_SAMPLES - 1u);
    __syncthreads();
    if (shDoneAll) {
        __threadfence();
        float d = 0.f, r = 0.f;
        if (tid < B_SAMPLES) {
            d = wsf[SAMP_OFF + tid * 2 + 0];
            r = wsf[SAMP_OFF + tid * 2 + 1];
        }
        for (int off = 32; off; off >>= 1) {
            d += __shfl_xor(d, off, 64);
            r += __shfl_xor(r, off, 64);
        }
        if (tid == 0) {
            out[0] = d * (1.0f / (2.0f * B_SAMPLES));
            out[1] = r * (1.0f / (B_SAMPLES * TOPK * TOPK));
        }
    }
}

extern "C" void kernel_launch(void* const* d_in, const int* in_sizes, int n_in,
                              void* d_out, int out_size, void* d_ws, size_t ws_size,
                              hipStream_t stream) {
    (void)in_sizes; (void)n_in; (void)out_size; (void)ws_size;
    const float* pred = (const float*)d_in[0];
    const float* tgt  = (const float*)d_in[1];
    float* wsf = (float*)d_ws;
    float* out = (float*)d_out;

    // zero the 32 padded per-sample done counters + global done (ws is 0xAA-poisoned)
    hipMemsetAsync((char*)d_ws + (size_t)SCTR_OFF * 4,
                   0, (B_SAMPLES * 16 + 1) * 4, stream);
    fused<<<NBLK, 256, 0, stream>>>(pred, tgt, wsf, out);
}

// Round 9
// 145.382 us; speedup vs baseline: 2.9297x; 2.9297x over previous
//
#include <hip/hip_runtime.h>

// Fusin_Dice_rank: fused 2-ch softmax + dice + top-30 rank hinge.
// Two-kernel structure (kernel boundary = free producer->consumer fence on
// multi-XCD CDNA; round-8 lesson: per-block __threadfence() in 2048 blocks
// costs ~350us in L2 writebacks).
// Keys: order-preserving u32 ord(d), d = x1-x0 (monotone with p=sigmoid(d)).
// t binary -> element feeds exactly ONE top-k problem:
//   A (t==0): key o=ordf(d);  B (t==1): key ~o = ordf(-d).
// passA (2048 blocks): stream, dice partials, static-threshold filter
//   (d>=3.5) with per-block LDS compaction -> TRANSPOSED candidate store
//   [CAP_B][2048] (coalesced passB gather). No global atomics, no fences.
// passB (32 blocks): wave0 dice, wave1/2 wave-local exact binary-search
//   top-30 (no barriers), hinge, sample store; last block (done ctr, 32
//   fences total) reduces 32 samples -> out. Exact whole-sample fallback if
//   filter under/overflows (unreachable on bench data).

#define N_ELEM (512 * 512)
#define B_SAMPLES 32
#define CHUNK 4096
#define BLOCKS_PER_S 64
#define NBLK (B_SAMPLES * BLOCKS_PER_S)   // 2048
#define TOPK 30
#define CAP_B 64            // per-block candidate cap (mean ~13.7, >10 sigma)
#define LCAP2 2048          // per-sample gather cap (mean ~874, >30 sigma)
// ordf(3.5f): 3.5f = 0x40600000, positive -> | 0x80000000
#define THR_KEY 0xC0600000u

// ws layout in u32 units
#define PART_OFF 0                                  // [2048][3] f32
#define CNTA_OFF (PART_OFF + NBLK * 3)              // [2048] u32
#define CNTB_OFF (CNTA_OFF + NBLK)                  // [2048] u32
#define CANDA_OFF (CNTB_OFF + NBLK)                 // [CAP_B][2048] u32 (transposed)
#define CANDB_OFF (CANDA_OFF + CAP_B * NBLK)
#define SAMP_OFF (CANDB_OFF + CAP_B * NBLK)         // [32][2] f32
#define DONE_OFF (SAMP_OFF + B_SAMPLES * 2)         // [1] u32

__device__ __forceinline__ unsigned ordf(float f) {
    unsigned u = __float_as_uint(f);
    return (u & 0x80000000u) ? ~u : (u | 0x80000000u);
}

__device__ __forceinline__ float invord_sigmoid(unsigned u) {
    if (u == 0u) return 0.0f;
    unsigned b = (u & 0x80000000u) ? (u ^ 0x80000000u) : ~u;
    float f = __uint_as_float(b);
    return 1.0f / (1.0f + __expf(-f));
}

__device__ __forceinline__ unsigned long long shflxor_u64(unsigned long long v, int off) {
    unsigned lo = (unsigned)v, hi = (unsigned)(v >> 32);
    lo = __shfl_xor(lo, off, 64);
    hi = __shfl_xor(hi, off, 64);
    return ((unsigned long long)hi << 32) | lo;
}

__global__ __launch_bounds__(256) void passA(const float* __restrict__ pred,
                                             const float* __restrict__ tgt,
                                             float* __restrict__ wsf) {
    unsigned* wsu = (unsigned*)wsf;
    const int s = blockIdx.x >> 6, c = blockIdx.x & 63;
    const int tid = threadIdx.x, lane = tid & 63, wid = tid >> 6;

    __shared__ float red[12];
    __shared__ int shCntA, shCntB;
    __shared__ unsigned LA_s[CAP_B], LB_s[CAP_B];

    if (tid == 0) { shCntA = 0; shCntB = 0; }
    if (blockIdx.x == 0 && tid == 0) wsu[DONE_OFF] = 0u;  // consumed only by passB

    const float* x0p = pred + (size_t)s * 2 * N_ELEM + (size_t)c * CHUNK;
    const float* x1p = x0p + N_ELEM;
    const float* tp  = tgt + (size_t)s * N_ELEM + (size_t)c * CHUNK;

    unsigned o[16];
    unsigned tmask = 0u;
    float sp = 0.f, spt = 0.f;

#pragma unroll
    for (int j = 0; j < 4; ++j) {
        float4 X0 = ((const float4*)x0p)[j * 256 + tid];
        float4 X1 = ((const float4*)x1p)[j * 256 + tid];
        float4 T  = ((const float4*)tp )[j * 256 + tid];
#define PROC(q, xx0, xx1, tt)                                  \
        {                                                      \
            float d = (xx1) - (xx0);                           \
            float p = 1.0f / (1.0f + __expf(-d));              \
            sp += p; spt = fmaf(p, (tt), spt);                 \
            o[j * 4 + (q)] = ordf(d);                          \
            if ((tt) != 0.0f) tmask |= 1u << (j * 4 + (q));    \
        }
        PROC(0, X0.x, X1.x, T.x)
        PROC(1, X0.y, X1.y, T.y)
        PROC(2, X0.z, X1.z, T.z)
        PROC(3, X0.w, X1.w, T.w)
#undef PROC
    }
    float st = (float)__popc(tmask);

    // dice partial sums (wave reduce)
    for (int off = 32; off; off >>= 1) {
        sp  += __shfl_xor(sp, off, 64);
        st  += __shfl_xor(st, off, 64);
        spt += __shfl_xor(spt, off, 64);
    }
    if (lane == 0) { red[wid * 3] = sp; red[wid * 3 + 1] = st; red[wid * 3 + 2] = spt; }
    __syncthreads();  // counters zeroed + red visible

    // static-threshold emit to per-block LDS buffers (~27 passers/block)
#pragma unroll
    for (int e = 0; e < 16; ++e) {
        unsigned key = o[e];
        if ((tmask >> e) & 1u) {
            unsigned kb = ~key;                        // == ordf(-d)
            if (kb >= THR_KEY) {
                int pos = atomicAdd(&shCntB, 1);
                if (pos < CAP_B) LB_s[pos] = kb;
            }
        } else {
            if (key >= THR_KEY) {
                int pos = atomicAdd(&shCntA, 1);
                if (pos < CAP_B) LA_s[pos] = key;
            }
        }
    }
    __syncthreads();

    const int blk = s * BLOCKS_PER_S + c;
    const int nA = shCntA, nB = shCntB;
    if (tid == 0) {
        float a = 0.f, b = 0.f, cc = 0.f;
#pragma unroll
        for (int w = 0; w < 4; ++w) { a += red[w * 3]; b += red[w * 3 + 1]; cc += red[w * 3 + 2]; }
        float* part = wsf + PART_OFF + (size_t)blk * 3;
        part[0] = a; part[1] = b; part[2] = cc;
        wsu[CNTA_OFF + blk] = (unsigned)nA;   // raw count: >CAP_B flags fallback
        wsu[CNTB_OFF + blk] = (unsigned)nB;
    }
    // transposed candidate store: item i of block blk at [i*NBLK + blk]
    if (tid < CAP_B) {
        if (tid < min(nA, CAP_B)) wsu[CANDA_OFF + (size_t)tid * NBLK + blk] = LA_s[tid];
        if (tid < min(nB, CAP_B)) wsu[CANDB_OFF + (size_t)tid * NBLK + blk] = LB_s[tid];
    }
}

// Exact top-30 fallback: 30 rounds of block argmax over the whole sample.
// Only if the threshold filter failed (unreachable on bench data).
__device__ void fallback30(const float* __restrict__ x0p, const float* __restrict__ x1p,
                           const float* __restrict__ tp, int isB, float* dst,
                           int tid, int lane, int wid, unsigned long long* sred) {
    unsigned long long prev = ~0ull;
    for (int r = 0; r < TOPK; ++r) {
        unsigned long long best = 0ull;
        for (int e = tid; e < N_ELEM; e += 256) {
            float d = x1p[e] - x0p[e];
            float t = tp[e];
            unsigned key;
            if (isB) key = (t != 0.0f) ? ordf(-d) : 0u;
            else     key = (t == 0.0f) ? ordf(d) : 0u;
            unsigned long long pk = ((unsigned long long)key << 18) | (unsigned)e;
            if (pk < prev && pk > best) best = pk;
        }
        for (int off = 32; off; off >>= 1) {
            unsigned long long v = shflxor_u64(best, off);
            if (v > best) best = v;
        }
        if (lane == 0) sred[wid] = best;
        __syncthreads();
        unsigned long long b0 = sred[0];
#pragma unroll
        for (int w = 1; w < 4; ++w) if (sred[w] > b0) b0 = sred[w];
        __syncthreads();
        if (tid == 0) dst[r] = invord_sigmoid((unsigned)(b0 >> 18));
        prev = b0;
    }
}

// Wave-local exact top-30 over one sample's TRANSPOSED candidate lists.
// candG = &ws[CAND?_OFF + s*64]: item i of block (s*64+lane) at
// candG[i*NBLK + lane] (coalesced across lanes). No barriers.
// flag: >=0 ok, -1 -> caller must run fallback.
__device__ void wave_select_t(const unsigned* __restrict__ candG,
                              const unsigned* __restrict__ cntG,   // [64]
                              unsigned* lbuf,                      // LDS [LCAP2]
                              unsigned* rbuf,                      // LDS [TOPK]
                              int* rcnt,                           // LDS, pre-zeroed
                              int* flag,                           // LDS
                              float* dst,                          // [TOPK]
                              int lane) {
    int cvr = (int)cntG[lane];
    int cv = min(cvr, CAP_B);
    unsigned long long ovb = __ballot(cvr > CAP_B);
    // inclusive scan of cv
    int pe = cv;
#pragma unroll
    for (int off = 1; off < 64; off <<= 1) {
        int v = __shfl_up(pe, off, 64);
        if (lane >= off) pe += v;
    }
    const int n = __shfl(pe, 63, 64);
    const int pf = pe - cv;
    if (n < TOPK || n > LCAP2 || ovb != 0ull) {
        if (lane == 0) *flag = -1;
        return;
    }
    if (lane == 0) *flag = n;
    // coalesced gather into LDS (same-wave LDS ordering suffices below)
    for (int i = 0; i < cv; ++i) lbuf[pf + i] = candG[i * NBLK + lane];
    // wave max to tighten the search range
    unsigned mx = 0u;
    for (int i = lane; i < n; i += 64) mx = max(mx, lbuf[i]);
#pragma unroll
    for (int off = 32; off; off >>= 1) mx = max(mx, (unsigned)__shfl_xor((int)mx, off, 64));
    // binary search: largest lo with count(key >= lo) >= TOPK
    unsigned lo = THR_KEY, hi = mx + 1u;
    while (hi - lo > 1u) {
        unsigned mid = lo + ((hi - lo) >> 1);
        int cnum = 0;
        for (int i = lane; i < n; i += 64) cnum += (lbuf[i] >= mid);
#pragma unroll
        for (int off = 32; off; off >>= 1) cnum += __shfl_xor(cnum, off, 64);
        if (cnum >= TOPK) lo = mid; else hi = mid;
    }
    // ch = count(key > lo) < TOPK; emit those, pad with copies of lo
    int ch = 0;
    for (int i = lane; i < n; i += 64) ch += (lbuf[i] > lo);
#pragma unroll
    for (int off = 32; off; off >>= 1) ch += __shfl_xor(ch, off, 64);
    for (int i = lane; i < n; i += 64) {
        unsigned k = lbuf[i];
        if (k > lo) { int pos = atomicAdd(rcnt, 1); rbuf[pos] = k; }
    }
    if (lane < TOPK - ch) rbuf[ch + lane] = lo;
    // deterministic rank-sort -> dst descending
    if (lane < TOPK) {
        unsigned key = rbuf[lane];
        int rank = 0;
#pragma unroll
        for (int j = 0; j < TOPK; ++j) {
            unsigned kj = rbuf[j];
            rank += (kj > key) || (kj == key && j < lane);
        }
        dst[rank] = invord_sigmoid(key);
    }
}

__global__ __launch_bounds__(256) void passB(const float* __restrict__ pred,
                                             const float* __restrict__ tgt,
                                             float* __restrict__ wsf,
                                             float* __restrict__ out) {
    unsigned* wsu = (unsigned*)wsf;
    const int s = blockIdx.x;
    const int tid = threadIdx.x, lane = tid & 63, wid = tid >> 6;

    __shared__ unsigned LA2[LCAP2], LB2[LCAP2];   // 16 KB
    __shared__ unsigned RA[TOPK], RB[TOPK];
    __shared__ int rcA, rcB, flagA, flagB, shDone;
    __shared__ float ntop[TOPK], pv[TOPK], fred[8];
    __shared__ unsigned long long sred[4];

    if (tid == 0) { rcA = 0; rcB = 0; flagA = 0; flagB = 0; }
    __syncthreads();

    if (wid == 0) {
        // dice sums over 64 chunk partials
        const float* part = wsf + PART_OFF + (size_t)(s * BLOCKS_PER_S + lane) * 3;
        float sp = part[0], st = part[1], spt = part[2];
        for (int off = 32; off; off >>= 1) {
            sp  += __shfl_xor(sp, off, 64);
            st  += __shfl_xor(st, off, 64);
            spt += __shfl_xor(spt, off, 64);
        }
        if (lane == 0) { fred[0] = sp; fred[1] = st; fred[2] = spt; }
    } else if (wid == 1) {
        wave_select_t(wsu + CANDA_OFF + s * BLOCKS_PER_S,
                      wsu + CNTA_OFF + s * BLOCKS_PER_S,
                      LA2, RA, &rcA, &flagA, ntop, lane);
    } else if (wid == 2) {
        wave_select_t(wsu + CANDB_OFF + s * BLOCKS_PER_S,
                      wsu + CNTB_OFF + s * BLOCKS_PER_S,
                      LB2, RB, &rcB, &flagB, pv, lane);
    }
    __syncthreads();

    // block-uniform fallbacks (unreachable on bench data)
    if (flagA < 0) {
        const float* b0 = pred + (size_t)s * 2 * N_ELEM;
        fallback30(b0, b0 + N_ELEM, tgt + (size_t)s * N_ELEM, 0, ntop, tid, lane, wid, sred);
    }
    if (flagB < 0) {
        const float* b0 = pred + (size_t)s * 2 * N_ELEM;
        fallback30(b0, b0 + N_ELEM, tgt + (size_t)s * N_ELEM, 1, pv, tid, lane, wid, sred);
    }
    __syncthreads();

    // 30x30 hinge sum
    float rs = 0.f;
    for (int pch = tid; pch < TOPK * TOPK; pch += 256) {
        int i = pch / TOPK, j = pch - i * TOPK;
        float th = ntop[i] - (1.0f - pv[j]) + 0.3f;
        rs += fmaxf(th, 0.0f);
    }
    for (int off = 32; off; off >>= 1) rs += __shfl_xor(rs, off, 64);
    if (lane == 0) fred[4 + wid] = rs;
    __syncthreads();

    if (tid == 0) {
        float SP = fred[0], ST = fred[1], SPT = fred[2];
        float RS = fred[4] + fred[5] + fred[6] + fred[7];
        const float Nf = (float)N_ELEM;
        float dice1 = 1.0f - 2.0f * SPT / (SP + ST + 1e-5f);
        float dice0 = 1.0f - 2.0f * (Nf - SP - ST + SPT) / ((Nf - SP) + (Nf - ST) + 1e-5f);
        float* samp = wsf + SAMP_OFF + s * 2;
        samp[0] = dice0 + dice1;
        samp[1] = RS;
    }
    __threadfence();   // only 32 blocks fence — cheap (round-8 lesson)
    if (tid == 0) shDone = atomicAdd((int*)&wsu[DONE_OFF], 1);
    __syncthreads();
    if (shDone == B_SAMPLES - 1) {
        __threadfence();
        float d = 0.f, r = 0.f;
        if (tid < B_SAMPLES) {
            d = wsf[SAMP_OFF + tid * 2 + 0];
            r = wsf[SAMP_OFF + tid * 2 + 1];
        }
        for (int off = 32; off; off >>= 1) {
            d += __shfl_xor(d, off, 64);
            r += __shfl_xor(r, off, 64);
        }
        if (tid == 0) {
            out[0] = d * (1.0f / (2.0f * B_SAMPLES));
            out[1] = r * (1.0f / (B_SAMPLES * TOPK * TOPK));
        }
    }
}

extern "C" void kernel_launch(void* const* d_in, const int* in_sizes, int n_in,
                              void* d_out, int out_size, void* d_ws, size_t ws_size,
                              hipStream_t stream) {
    (void)in_sizes; (void)n_in; (void)out_size; (void)ws_size;
    const float* pred = (const float*)d_in[0];
    const float* tgt  = (const float*)d_in[1];
    float* wsf = (float*)d_ws;
    float* out = (float*)d_out;

    passA<<<NBLK, 256, 0, stream>>>(pred, tgt, wsf);
    passB<<<B_SAMPLES, 256, 0, stream>>>(pred, tgt, wsf, out);
}